// Round 1
// 616.305 us; speedup vs baseline: 1.0155x; 1.0155x over previous
//
#include <hip/hip_runtime.h>
#include <math.h>

#define BB 64
#define NN 1024
#define DD 1024

typedef __bf16 bf16x8 __attribute__((ext_vector_type(8)));
typedef _Float16 f16x8 __attribute__((ext_vector_type(8)));
typedef float f32x4 __attribute__((ext_vector_type(4)));
typedef unsigned short u16x8 __attribute__((ext_vector_type(8)));

#define GLOAD_LDS16(g, l)                                                  \
    __builtin_amdgcn_global_load_lds(                                      \
        (const __attribute__((address_space(1))) unsigned int*)(g),        \
        (__attribute__((address_space(3))) unsigned int*)(l), 16, 0, 0)

__device__ __forceinline__ float fast_tanh(float x) {
    return 1.f - 2.f / (__expf(2.f * x) + 1.f);
}

// ws layout:
//   qh      fp32 [BB*DD]                     @ 0
//   scores  fp32 [BB*NN]                     @ 65536 floats
//   wkT     fp16 [8 et][32 kt][128*32]       @ byte 524288   (2 MB)
//   keysT   fp16 [64 b][8 nt][32 kt][128*32] @ byte 2621440  (128 MB)
//
// SWIZZLE: within each 64-byte row of a [128][32]-f16 tile, the four 16-byte
// sub-blocks are permuted: sub' = sub ^ ((row>>1)&3). Producer (k_cvt) writes
// pre-swizzled; k_sc stages linearly via global_load_lds and applies the same
// XOR on ds_read addresses (conflict-free b128: every consecutive lane octet
// covers all 8 four-bank groups); k_ctx relabels which k-octet it holds.

// ---- k_cvt: keys (and W_k as bb==64) fp32 -> fp16 tiled+swizzled chunks ----
// grid (8 nt, 65 bb, 4 ks); each block does 8 kt chunks. Wave writes 1 KB contiguous.
__global__ __launch_bounds__(256) void k_cvt(const float* __restrict__ keys,
                                             const float* __restrict__ W_k,
                                             _Float16* __restrict__ keysT,
                                             _Float16* __restrict__ wkT) {
    const int nt = blockIdx.x;  // 8
    const int bb = blockIdx.y;  // 0..64 (64 = W_k)
    const int ks = blockIdx.z;  // 0..3
    const int t = threadIdx.x;
    const float* src = (bb == 64) ? (W_k + (size_t)nt * 128 * DD)
                                  : (keys + ((size_t)bb * NN + nt * 128) * DD);
    _Float16* dst = (bb == 64) ? (wkT + (size_t)nt * 32 * 4096)
                               : (keysT + (((size_t)bb * 8 + nt) * 32) * 4096);
    const int p0 = t * 8;
    const int n0 = p0 >> 5;      // row within 64-row half
    const int k0 = p0 & 31;      // k-octet start
    // swizzled write sub-block: q' = q ^ ((row>>1)&3); row bits 1-2 == n0 bits 1-2
    const int ksw = (k0 >> 3) ^ ((n0 >> 1) & 3);
    for (int kt = ks * 8; kt < ks * 8 + 8; ++kt) {
#pragma unroll
        for (int r = 0; r < 2; ++r) {
            const int n = n0 + r * 64;
            const float4* s4 = (const float4*)(src + (size_t)n * DD + kt * 32 + k0);
            float4 a = s4[0], b4 = s4[1];
            f16x8 h = {(_Float16)a.x,  (_Float16)a.y,  (_Float16)a.z,  (_Float16)a.w,
                       (_Float16)b4.x, (_Float16)b4.y, (_Float16)b4.z, (_Float16)b4.w};
            *(f16x8*)(dst + (size_t)kt * 4096 + n * 32 + ksw * 8) = h;
        }
    }
}

// ---- k_qh: qh[b, et*128..+128] = h_t[b] @ W_h.T slice; zeroes scores slice ----
// grid (64 b, 8 et): b fastest -> all XCDs stream the same W_h slice (L2/L3-served).
__global__ __launch_bounds__(256) void k_qh(const float* __restrict__ h_t,
                                            const float* __restrict__ W_h,
                                            float* __restrict__ qh,
                                            float* __restrict__ scores) {
    __shared__ float hs[DD];
    __shared__ float red2[128];
    const int b = blockIdx.x;   // 0..63
    const int et = blockIdx.y;  // 0..7
    const int t = threadIdx.x;
    if (t < 128) scores[b * NN + et * 128 + t] = 0.f;
    ((float4*)hs)[t] = ((const float4*)(h_t + (size_t)b * DD))[t];
    __syncthreads();
    const int el = t & 127;
    const int half = t >> 7;
    const int e = et * 128 + el;
    const float4* wrow = (const float4*)(W_h + (size_t)e * DD) + half * 128;
    const float* hp = hs + half * 512;
    float acc = 0.f;
#pragma unroll 4
    for (int k4 = 0; k4 < 128; ++k4) {
        float4 wv = wrow[k4];
        acc = fmaf(wv.x, hp[4 * k4 + 0], acc);
        acc = fmaf(wv.y, hp[4 * k4 + 1], acc);
        acc = fmaf(wv.z, hp[4 * k4 + 2], acc);
        acc = fmaf(wv.w, hp[4 * k4 + 3], acc);
    }
    if (half == 1) red2[el] = acc;
    __syncthreads();
    if (half == 0) qh[(size_t)b * DD + e] = acc + red2[el];
}

// ---- k_sc: fp16 MFMA GEMM, BK=64, XCD-swizzled grid, fused tanh/v epilogue ----
// grid (64, 64): bx = cp*8 + nt (keys tile shared by ids = same mod 8 -> same XCD), by = b.
__global__ __launch_bounds__(256, 4) void k_sc(const _Float16* __restrict__ keysT,
                                               const _Float16* __restrict__ wkT,
                                               const float* __restrict__ v,
                                               const float* __restrict__ qh,
                                               float* __restrict__ scores) {
    __shared__ _Float16 As[2 * 128 * 32];  // 16 KB
    __shared__ _Float16 Bs[2 * 128 * 32];
    __shared__ float vs[128];
    __shared__ float qs[128];
    __shared__ float red[128][2];

    const int tid = threadIdx.x;
    const int cp = blockIdx.x >> 3;  // e-tile 0..7
    const int nt = blockIdx.x & 7;   // n-tile 0..7
    const int b = blockIdx.y;
    const int e0 = cp * 128;

    if (tid < 128) {
        vs[tid] = v[e0 + tid];
        qs[tid] = qh[b * DD + e0 + tid];
    }

    const char* Abase = (const char*)(keysT + (((size_t)b * 8 + nt) * 32) * 4096);
    const char* Bbase = (const char*)(wkT + ((size_t)cp * 32) * 4096);

    const int w = tid >> 6;
    const int lane = tid & 63;
    const int wm = w & 1;
    const int we = w >> 1;
    const int lcol = lane & 15;
    const int quad = lane >> 4;
    const int soff = tid * 16;
    // read-side swizzle: row = *64 + *16 + lcol, so (row>>1)&3 == (lcol>>1)&3
    const int qx = quad ^ ((lcol >> 1) & 3);

    f32x4 acc[4][4];
#pragma unroll
    for (int mi = 0; mi < 4; ++mi)
#pragma unroll
        for (int ni = 0; ni < 4; ++ni) acc[mi][ni] = (f32x4){0.f, 0.f, 0.f, 0.f};

    for (int kt2 = 0; kt2 < 16; ++kt2) {  // BK=64: two 8 KB chunks per side
        __syncthreads();
        const char* ag = Abase + (size_t)kt2 * 16384 + soff;
        const char* bg = Bbase + (size_t)kt2 * 16384 + soff;
        char* al_ = (char*)As + soff;
        char* bl_ = (char*)Bs + soff;
#pragma unroll
        for (int r = 0; r < 4; ++r) GLOAD_LDS16(ag + r * 4096, al_ + r * 4096);
#pragma unroll
        for (int r = 0; r < 4; ++r) GLOAD_LDS16(bg + r * 4096, bl_ + r * 4096);
        __syncthreads();

#pragma unroll
        for (int c = 0; c < 2; ++c) {
            f16x8 af[4], bf[4];
#pragma unroll
            for (int mi = 0; mi < 4; ++mi)
                af[mi] = *(const f16x8*)&As[c * 4096 + (wm * 64 + mi * 16 + lcol) * 32 + qx * 8];
#pragma unroll
            for (int ni = 0; ni < 4; ++ni)
                bf[ni] = *(const f16x8*)&Bs[c * 4096 + (we * 64 + ni * 16 + lcol) * 32 + qx * 8];
#pragma unroll
            for (int mi = 0; mi < 4; ++mi)
#pragma unroll
                for (int ni = 0; ni < 4; ++ni)
                    acc[mi][ni] = __builtin_amdgcn_mfma_f32_16x16x32_f16(af[mi], bf[ni], acc[mi][ni], 0, 0, 0);
        }
    }

    // epilogue: C/D layout col=lane&15 (e), row=quad*4+reg (n)
    float part[4][4];
#pragma unroll
    for (int mi = 0; mi < 4; ++mi)
#pragma unroll
        for (int r = 0; r < 4; ++r) part[mi][r] = 0.f;
#pragma unroll
    for (int mi = 0; mi < 4; ++mi)
#pragma unroll
        for (int ni = 0; ni < 4; ++ni) {
            const int e = we * 64 + ni * 16 + lcol;
            const float vv = vs[e];
            const float qv = qs[e];
#pragma unroll
            for (int r = 0; r < 4; ++r)
                part[mi][r] += vv * fast_tanh(qv + acc[mi][ni][r]);
        }
#pragma unroll
    for (int mi = 0; mi < 4; ++mi)
#pragma unroll
        for (int r = 0; r < 4; ++r) {
            float p = part[mi][r];
            p += __shfl_xor(p, 1);
            p += __shfl_xor(p, 2);
            p += __shfl_xor(p, 4);
            p += __shfl_xor(p, 8);
            if (lcol == 0) red[wm * 64 + mi * 16 + quad * 4 + r][we] = p;
        }
    __syncthreads();
    if (tid < 128) atomicAdd(&scores[b * NN + nt * 128 + tid], red[tid][0] + red[tid][1]);
}

// ---- k_sm: softmax; zeroes nothing (context written directly by k_ctx) ----
__global__ __launch_bounds__(256) void k_sm(const float* __restrict__ scores,
                                            float* __restrict__ alpha) {
    const int b = blockIdx.x;
    const int t = threadIdx.x;
    float x[4];
    float m = -1e30f;
#pragma unroll
    for (int j = 0; j < 4; ++j) {
        x[j] = scores[b * NN + t + 256 * j];
        m = fmaxf(m, x[j]);
    }
#pragma unroll
    for (int mask = 32; mask >= 1; mask >>= 1) m = fmaxf(m, __shfl_xor(m, mask));
    __shared__ float wred[4];
    __shared__ float wsum[4];
    const int wv = t >> 6;
    if ((t & 63) == 0) wred[wv] = m;
    __syncthreads();
    m = fmaxf(fmaxf(wred[0], wred[1]), fmaxf(wred[2], wred[3]));
    float s = 0.f;
#pragma unroll
    for (int j = 0; j < 4; ++j) {
        x[j] = expf(x[j] - m);
        s += x[j];
    }
#pragma unroll
    for (int mask = 32; mask >= 1; mask >>= 1) s += __shfl_xor(s, mask);
    if ((t & 63) == 0) wsum[wv] = s;
    __syncthreads();
    s = wsum[0] + wsum[1] + wsum[2] + wsum[3];
    const float inv = 1.f / s;
#pragma unroll
    for (int j = 0; j < 4; ++j) alpha[b * NN + t + 256 * j] = x[j] * inv;
}

// ---- k_ctx: context[b, kt*32..+32] = sum_n alpha[b,n]*keysT chunks; no atomics ----
// grid (32 kt, 64 b). Coalesced 8 KB chunk reads; LDS tree reduce; exclusive d-range.
// Swizzle-aware: sub-block q of row g holds k-octet q ^ ((g>>1)&3).
__global__ __launch_bounds__(256) void k_ctx(const _Float16* __restrict__ keysT,
                                             const float* __restrict__ alpha,
                                             float* __restrict__ context) {
    __shared__ float al[NN];
    __shared__ float red[64][33];
    const int kt = blockIdx.x;  // 0..31
    const int b = blockIdx.y;   // 0..63
    const int t = threadIdx.x;
#pragma unroll
    for (int j = 0; j < 4; ++j) al[t + 256 * j] = alpha[b * NN + t + 256 * j];
    __syncthreads();

    const int p0 = t * 8;
    const int g = t >> 2;         // 0..63: n within half-chunk
    const int q = t & 3;          // physical sub-block
    const int qe = q ^ ((g >> 1) & 3);  // logical k-octet held (swizzle relabel)
    float acc[8];
#pragma unroll
    for (int j = 0; j < 8; ++j) acc[j] = 0.f;

    for (int nt = 0; nt < 8; ++nt) {
        const _Float16* base = keysT + (((size_t)b * 8 + nt) * 32 + kt) * 4096;
#pragma unroll
        for (int r = 0; r < 2; ++r) {
            f16x8 kv = *(const f16x8*)(base + r * 2048 + p0);
            const float a = al[nt * 128 + r * 64 + g];
#pragma unroll
            for (int j = 0; j < 8; ++j) acc[j] = fmaf(a, (float)kv[j], acc[j]);
        }
    }
#pragma unroll
    for (int j = 0; j < 8; ++j) red[g][qe * 8 + j] = acc[j];
    __syncthreads();
    if (t < 32) {
        float s = 0.f;
#pragma unroll 8
        for (int n = 0; n < 64; ++n) s += red[n][t];
        context[(size_t)b * DD + kt * 32 + t] = s;
    }
}

// =========================== FALLBACK PATH (used if ws too small) ===========================
__global__ __launch_bounds__(256) void qh_fb(const float* __restrict__ h_t,
                                             const float* __restrict__ W_h,
                                             float* __restrict__ qh,
                                             float* __restrict__ scores) {
    __shared__ float hs[DD];
    const int b = blockIdx.y;
    const int e = blockIdx.x * 256 + threadIdx.x;
    scores[(blockIdx.y * 4 + blockIdx.x) * 256 + threadIdx.x] = 0.f;
    for (int i = threadIdx.x; i < DD; i += 256) hs[i] = h_t[b * DD + i];
    __syncthreads();
    const float4* wrow = (const float4*)(W_h + (size_t)e * DD);
    float acc = 0.f;
#pragma unroll 4
    for (int k4 = 0; k4 < DD / 4; ++k4) {
        float4 w = wrow[k4];
        acc = fmaf(w.x, hs[4 * k4 + 0], acc);
        acc = fmaf(w.y, hs[4 * k4 + 1], acc);
        acc = fmaf(w.z, hs[4 * k4 + 2], acc);
        acc = fmaf(w.w, hs[4 * k4 + 3], acc);
    }
    qh[b * DD + e] = acc;
}

#define SPAD 40
__device__ __forceinline__ void split16(const float4* __restrict__ src,
                                        unsigned short* hi, unsigned short* lo) {
    float x[16];
    float4 v0 = src[0], v1 = src[1], v2 = src[2], v3 = src[3];
    x[0] = v0.x; x[1] = v0.y; x[2] = v0.z; x[3] = v0.w;
    x[4] = v1.x; x[5] = v1.y; x[6] = v1.z; x[7] = v1.w;
    x[8] = v2.x; x[9] = v2.y; x[10] = v2.z; x[11] = v2.w;
    x[12] = v3.x; x[13] = v3.y; x[14] = v3.z; x[15] = v3.w;
#pragma unroll
    for (int i = 0; i < 16; ++i) {
        unsigned int u = __float_as_uint(x[i]);
        hi[i] = (unsigned short)(u >> 16);
        float hif = __uint_as_float(u & 0xFFFF0000u);
        float lof = x[i] - hif;
        lo[i] = (unsigned short)(__float_as_uint(lof) >> 16);
    }
}

__global__ __launch_bounds__(256, 2) void scores_fb(const float* __restrict__ keys,
                                                    const float* __restrict__ W_k,
                                                    const float* __restrict__ v,
                                                    const float* __restrict__ qh,
                                                    float* __restrict__ scores) {
    __shared__ unsigned short Ah[128 * SPAD];
    __shared__ unsigned short Al[128 * SPAD];
    __shared__ unsigned short Bh[128 * SPAD];
    __shared__ unsigned short Bl[128 * SPAD];
    __shared__ float vs[128];
    __shared__ float qs[128];
    __shared__ float red[128][2];

    const int tid = threadIdx.x;
    const int cp = blockIdx.x;
    const int rt = blockIdx.y;
    const int b = rt >> 3;
    const int n0 = (rt & 7) * 128;
    const int e0 = cp * 128;
    if (tid < 128) {
        vs[tid] = v[e0 + tid];
        qs[tid] = qh[b * DD + e0 + tid];
    }
    const float* Ag = keys + ((size_t)b * NN + n0) * DD;
    const float* Bg = W_k + (size_t)e0 * DD;
    const int w = tid >> 6;
    const int lane = tid & 63;
    const int wm = w & 1;
    const int we = w >> 1;
    const int lcol = lane & 15;
    const int quad = lane >> 4;
    f32x4 acc[4][4];
#pragma unroll
    for (int mi = 0; mi < 4; ++mi)
#pragma unroll
        for (int ni = 0; ni < 4; ++ni) acc[mi][ni] = (f32x4){0.f, 0.f, 0.f, 0.f};
    const int srow = tid >> 1;
    const int sseg = tid & 1;
    float4 pa[4], pb[4];
    {
        const float4* as = (const float4*)(Ag + (size_t)srow * DD + sseg * 16);
        const float4* bs = (const float4*)(Bg + (size_t)srow * DD + sseg * 16);
#pragma unroll
        for (int i = 0; i < 4; ++i) { pa[i] = as[i]; pb[i] = bs[i]; }
    }
    for (int kt = 0; kt < DD / 32; ++kt) {
        __syncthreads();
        {
            unsigned short hi[16], lo[16];
            split16(pa, hi, lo);
            u16x8* dh = (u16x8*)&Ah[srow * SPAD + sseg * 16];
            u16x8* dl = (u16x8*)&Al[srow * SPAD + sseg * 16];
            dh[0] = *(u16x8*)&hi[0]; dh[1] = *(u16x8*)&hi[8];
            dl[0] = *(u16x8*)&lo[0]; dl[1] = *(u16x8*)&lo[8];
            split16(pb, hi, lo);
            u16x8* eh = (u16x8*)&Bh[srow * SPAD + sseg * 16];
            u16x8* el = (u16x8*)&Bl[srow * SPAD + sseg * 16];
            eh[0] = *(u16x8*)&hi[0]; eh[1] = *(u16x8*)&hi[8];
            el[0] = *(u16x8*)&lo[0]; el[1] = *(u16x8*)&lo[8];
        }
        if (kt + 1 < DD / 32) {
            const int k0 = (kt + 1) * 32;
            const float4* as = (const float4*)(Ag + (size_t)srow * DD + k0 + sseg * 16);
            const float4* bs = (const float4*)(Bg + (size_t)srow * DD + k0 + sseg * 16);
#pragma unroll
            for (int i = 0; i < 4; ++i) { pa[i] = as[i]; pb[i] = bs[i]; }
        }
        __syncthreads();
        bf16x8 ah[4], al2[4], bh[4], bl2[4];
#pragma unroll
        for (int mi = 0; mi < 4; ++mi) {
            const int r = wm * 64 + mi * 16 + lcol;
            ah[mi] = *(const bf16x8*)&Ah[r * SPAD + quad * 8];
            al2[mi] = *(const bf16x8*)&Al[r * SPAD + quad * 8];
        }
#pragma unroll
        for (int ni = 0; ni < 4; ++ni) {
            const int r = we * 64 + ni * 16 + lcol;
            bh[ni] = *(const bf16x8*)&Bh[r * SPAD + quad * 8];
            bl2[ni] = *(const bf16x8*)&Bl[r * SPAD + quad * 8];
        }
#pragma unroll
        for (int mi = 0; mi < 4; ++mi)
#pragma unroll
            for (int ni = 0; ni < 4; ++ni) {
                acc[mi][ni] = __builtin_amdgcn_mfma_f32_16x16x32_bf16(ah[mi], bh[ni], acc[mi][ni], 0, 0, 0);
                acc[mi][ni] = __builtin_amdgcn_mfma_f32_16x16x32_bf16(ah[mi], bl2[ni], acc[mi][ni], 0, 0, 0);
                acc[mi][ni] = __builtin_amdgcn_mfma_f32_16x16x32_bf16(al2[mi], bh[ni], acc[mi][ni], 0, 0, 0);
            }
    }
    float part[4][4];
#pragma unroll
    for (int mi = 0; mi < 4; ++mi)
#pragma unroll
        for (int r = 0; r < 4; ++r) part[mi][r] = 0.f;
#pragma unroll
    for (int mi = 0; mi < 4; ++mi)
#pragma unroll
        for (int ni = 0; ni < 4; ++ni) {
            const int e = we * 64 + ni * 16 + lcol;
            const float vv = vs[e];
            const float qv = qs[e];
#pragma unroll
            for (int r = 0; r < 4; ++r)
                part[mi][r] += vv * fast_tanh(qv + acc[mi][ni][r]);
        }
#pragma unroll
    for (int mi = 0; mi < 4; ++mi)
#pragma unroll
        for (int r = 0; r < 4; ++r) {
            float p = part[mi][r];
            p += __shfl_xor(p, 1);
            p += __shfl_xor(p, 2);
            p += __shfl_xor(p, 4);
            p += __shfl_xor(p, 8);
            if (lcol == 0) red[wm * 64 + mi * 16 + quad * 4 + r][we] = p;
        }
    __syncthreads();
    if (tid < 128) atomicAdd(&scores[b * NN + n0 + tid], red[tid][0] + red[tid][1]);
}

__global__ __launch_bounds__(256) void sm_fb(const float* __restrict__ scores,
                                             float* __restrict__ alpha,
                                             float* __restrict__ context) {
    const int b = blockIdx.x;
    const int t = threadIdx.x;
#pragma unroll
    for (int j = 0; j < 4; ++j) context[b * DD + t + 256 * j] = 0.f;
    float x[4];
    float m = -1e30f;
#pragma unroll
    for (int j = 0; j < 4; ++j) {
        x[j] = scores[b * NN + t + 256 * j];
        m = fmaxf(m, x[j]);
    }
#pragma unroll
    for (int mask = 32; mask >= 1; mask >>= 1) m = fmaxf(m, __shfl_xor(m, mask));
    __shared__ float wred[4];
    __shared__ float wsum[4];
    const int wv = t >> 6;
    if ((t & 63) == 0) wred[wv] = m;
    __syncthreads();
    m = fmaxf(fmaxf(wred[0], wred[1]), fmaxf(wred[2], wred[3]));
    float s = 0.f;
#pragma unroll
    for (int j = 0; j < 4; ++j) {
        x[j] = expf(x[j] - m);
        s += x[j];
    }
#pragma unroll
    for (int mask = 32; mask >= 1; mask >>= 1) s += __shfl_xor(s, mask);
    if ((t & 63) == 0) wsum[wv] = s;
    __syncthreads();
    s = wsum[0] + wsum[1] + wsum[2] + wsum[3];
    const float inv = 1.f / s;
#pragma unroll
    for (int j = 0; j < 4; ++j) alpha[b * NN + t + 256 * j] = x[j] * inv;
}

__global__ __launch_bounds__(256) void ctx_fb(const float* __restrict__ keys,
                                              const float* __restrict__ alpha,
                                              float* __restrict__ context) {
    const int b = blockIdx.y;
    const int nc = blockIdx.x;
    const int t = threadIdx.x;
    __shared__ float al[64];
    if (t < 64) al[t] = alpha[b * NN + nc * 64 + t];
    __syncthreads();
    const float4* kp = (const float4*)(keys + ((size_t)b * NN + nc * 64) * DD);
    float4 acc = {0.f, 0.f, 0.f, 0.f};
#pragma unroll 4
    for (int n = 0; n < 64; ++n) {
        const float a = al[n];
        float4 kv = kp[(size_t)n * (DD / 4) + t];
        acc.x = fmaf(a, kv.x, acc.x);
        acc.y = fmaf(a, kv.y, acc.y);
        acc.z = fmaf(a, kv.z, acc.z);
        acc.w = fmaf(a, kv.w, acc.w);
    }
    float* cp = context + b * DD + 4 * t;
    atomicAdd(cp + 0, acc.x);
    atomicAdd(cp + 1, acc.y);
    atomicAdd(cp + 2, acc.z);
    atomicAdd(cp + 3, acc.w);
}

extern "C" void kernel_launch(void* const* d_in, const int* in_sizes, int n_in,
                              void* d_out, int out_size, void* d_ws, size_t ws_size,
                              hipStream_t stream) {
    const float* h_t = (const float*)d_in[0];
    const float* keys = (const float*)d_in[1];
    const float* W_h = (const float*)d_in[2];
    const float* W_k = (const float*)d_in[3];
    const float* v = (const float*)d_in[4];

    float* context = (float*)d_out;          // [B, D]
    float* alpha = (float*)d_out + BB * DD;  // [B, N]
    float* qh = (float*)d_ws;                // [B, D]
    float* scores = (float*)d_ws + BB * DD;  // [B, N]

    const size_t wkT_off = (size_t)2 * BB * DD * sizeof(float);  // 512 KB
    const size_t keysT_off = wkT_off + (size_t)DD * DD * 2;      // +2 MB
    const size_t need = keysT_off + (size_t)BB * NN * DD * 2;    // +128 MB

    if (ws_size >= need) {
        _Float16* wkT = (_Float16*)((char*)d_ws + wkT_off);
        _Float16* keysT = (_Float16*)((char*)d_ws + keysT_off);
        k_cvt<<<dim3(8, 65, 4), 256, 0, stream>>>(keys, W_k, keysT, wkT);
        k_qh<<<dim3(64, 8), 256, 0, stream>>>(h_t, W_h, qh, scores);
        k_sc<<<dim3(64, 64), 256, 0, stream>>>(keysT, wkT, v, qh, scores);
        k_sm<<<BB, 256, 0, stream>>>(scores, alpha);
        k_ctx<<<dim3(32, 64), 256, 0, stream>>>(keysT, alpha, context);
    } else {
        qh_fb<<<dim3(4, BB), 256, 0, stream>>>(h_t, W_h, qh, scores);
        scores_fb<<<dim3(8, 512), 256, 0, stream>>>(keys, W_k, v, qh, scores);
        sm_fb<<<BB, 256, 0, stream>>>(scores, alpha, context);
        ctx_fb<<<dim3(16, BB), 256, 0, stream>>>(keys, alpha, context);
    }
}

// Round 2
// 609.713 us; speedup vs baseline: 1.0265x; 1.0108x over previous
//
#include <hip/hip_runtime.h>
#include <math.h>

#define BB 64
#define NN 1024
#define DD 1024

typedef __bf16 bf16x8 __attribute__((ext_vector_type(8)));
typedef _Float16 f16x8 __attribute__((ext_vector_type(8)));
typedef float f32x4 __attribute__((ext_vector_type(4)));
typedef unsigned short u16x8 __attribute__((ext_vector_type(8)));

#define GLOAD_LDS16(g, l)                                                  \
    __builtin_amdgcn_global_load_lds(                                      \
        (const __attribute__((address_space(1))) unsigned int*)(g),        \
        (__attribute__((address_space(3))) unsigned int*)(l), 16, 0, 0)

__device__ __forceinline__ float fast_tanh(float x) {
    return 1.f - 2.f / (__expf(2.f * x) + 1.f);
}

// ws layout:
//   qh      fp32 [BB*DD]                     @ 0
//   scores  fp32 [BB*NN]                     @ 65536 floats
//   wkT     fp16 [8 et][32 kt][128*32]       @ byte 524288   (2 MB)
//   keysT   fp16 [64 b][8 nt][32 kt][128*32] @ byte 2621440  (128 MB)
//
// SWIZZLE: within each 64-byte row of a [128][32]-f16 chunk, the four 16-byte
// sub-blocks are permuted: sub' = sub ^ ((row>>1)&3). Producer (k_cvt) writes
// pre-swizzled; k_sc stages linearly via global_load_lds and applies the same
// XOR on ds_read addresses (conflict-free b128); k_ctx relabels k-octets.

// ---- k_cvt: keys (and W_k as bb==64) fp32 -> fp16 tiled+swizzled chunks ----
__global__ __launch_bounds__(256) void k_cvt(const float* __restrict__ keys,
                                             const float* __restrict__ W_k,
                                             _Float16* __restrict__ keysT,
                                             _Float16* __restrict__ wkT) {
    const int nt = blockIdx.x;  // 8
    const int bb = blockIdx.y;  // 0..64 (64 = W_k)
    const int ks = blockIdx.z;  // 0..3
    const int t = threadIdx.x;
    const float* src = (bb == 64) ? (W_k + (size_t)nt * 128 * DD)
                                  : (keys + ((size_t)bb * NN + nt * 128) * DD);
    _Float16* dst = (bb == 64) ? (wkT + (size_t)nt * 32 * 4096)
                               : (keysT + (((size_t)bb * 8 + nt) * 32) * 4096);
    const int p0 = t * 8;
    const int n0 = p0 >> 5;      // row within 64-row half
    const int k0 = p0 & 31;      // k-octet start
    const int ksw = (k0 >> 3) ^ ((n0 >> 1) & 3);
    for (int kt = ks * 8; kt < ks * 8 + 8; ++kt) {
#pragma unroll
        for (int r = 0; r < 2; ++r) {
            const int n = n0 + r * 64;
            const float4* s4 = (const float4*)(src + (size_t)n * DD + kt * 32 + k0);
            float4 a = s4[0], b4 = s4[1];
            f16x8 h = {(_Float16)a.x,  (_Float16)a.y,  (_Float16)a.z,  (_Float16)a.w,
                       (_Float16)b4.x, (_Float16)b4.y, (_Float16)b4.z, (_Float16)b4.w};
            *(f16x8*)(dst + (size_t)kt * 4096 + n * 32 + ksw * 8) = h;
        }
    }
}

// ---- k_qh: qh[b, et*128..+128] = h_t[b] @ W_h.T slice; zeroes scores slice ----
__global__ __launch_bounds__(256) void k_qh(const float* __restrict__ h_t,
                                            const float* __restrict__ W_h,
                                            float* __restrict__ qh,
                                            float* __restrict__ scores) {
    __shared__ float hs[DD];
    __shared__ float red2[128];
    const int b = blockIdx.x;   // 0..63
    const int et = blockIdx.y;  // 0..7
    const int t = threadIdx.x;
    if (t < 128) scores[b * NN + et * 128 + t] = 0.f;
    ((float4*)hs)[t] = ((const float4*)(h_t + (size_t)b * DD))[t];
    __syncthreads();
    const int el = t & 127;
    const int half = t >> 7;
    const int e = et * 128 + el;
    const float4* wrow = (const float4*)(W_h + (size_t)e * DD) + half * 128;
    const float* hp = hs + half * 512;
    float acc = 0.f;
#pragma unroll 4
    for (int k4 = 0; k4 < 128; ++k4) {
        float4 wv = wrow[k4];
        acc = fmaf(wv.x, hp[4 * k4 + 0], acc);
        acc = fmaf(wv.y, hp[4 * k4 + 1], acc);
        acc = fmaf(wv.z, hp[4 * k4 + 2], acc);
        acc = fmaf(wv.w, hp[4 * k4 + 3], acc);
    }
    if (half == 1) red2[el] = acc;
    __syncthreads();
    if (half == 0) qh[(size_t)b * DD + e] = acc + red2[el];
}

// ---- k_sc: 256x256-tile fp16 MFMA GEMM, 4-deep pipelined (T3+T4+T5) ----
// grid 1024 (bijective XCD swizzle), 512 thr = 8 waves (2m x 4n), 128x64/wave.
// Per K-slab (BK=32) phase: ds_read 12xb128 | stage slab kt+3 (4x gload_lds16)
// | lgkmcnt(0) | 32 MFMA (setprio) | counted vmcnt(8) | s_barrier. Never
// drains vmcnt to 0 in the main loop.
#define PHASE(KT, SLAB, VM)                                                   \
    do {                                                                      \
        const _Float16* ab = As + ((KT) & 3) * 8192 + aofs;                   \
        const _Float16* bb2 = Bs + ((KT) & 3) * 8192 + bofs;                  \
        f16x8 af[8], bf[4];                                                   \
        _Pragma("unroll") for (int mi = 0; mi < 8; ++mi)                      \
            af[mi] = *(const f16x8*)(ab + mi * 512);                          \
        _Pragma("unroll") for (int ni = 0; ni < 4; ++ni)                      \
            bf[ni] = *(const f16x8*)(bb2 + ni * 512);                         \
        if ((SLAB) < 32) {                                                    \
            const size_t go = (size_t)(SLAB) * 8192;                          \
            const int sl = (SLAB) & 3;                                        \
            GLOAD_LDS16(a0 + go, AsB + sl * 16384 + tid * 16);                \
            GLOAD_LDS16(a1 + go, AsB + sl * 16384 + 8192 + tid * 16);         \
            GLOAD_LDS16(b0 + go, BsB + sl * 16384 + tid * 16);                \
            GLOAD_LDS16(b1 + go, BsB + sl * 16384 + 8192 + tid * 16);         \
        }                                                                     \
        asm volatile("s_waitcnt lgkmcnt(0)" ::: "memory");                    \
        __builtin_amdgcn_sched_barrier(0);                                    \
        __builtin_amdgcn_s_setprio(1);                                        \
        _Pragma("unroll") for (int mi = 0; mi < 8; ++mi)                      \
            _Pragma("unroll") for (int ni = 0; ni < 4; ++ni)                  \
                acc[mi][ni] = __builtin_amdgcn_mfma_f32_16x16x32_f16(         \
                    af[mi], bf[ni], acc[mi][ni], 0, 0, 0);                    \
        __builtin_amdgcn_s_setprio(0);                                        \
        asm volatile(VM ::: "memory");                                        \
        __builtin_amdgcn_s_barrier();                                         \
        __builtin_amdgcn_sched_barrier(0);                                    \
    } while (0)

__global__ __launch_bounds__(512, 2) void k_sc(const _Float16* __restrict__ keysT,
                                               const _Float16* __restrict__ wkT,
                                               const float* __restrict__ v,
                                               const float* __restrict__ qh,
                                               float* __restrict__ scores) {
    __shared__ _Float16 As[4 * 8192];  // 4 slots x [2 half][128 rows][32 k] = 64 KB
    __shared__ _Float16 Bs[4 * 8192];  // 64 KB
    __shared__ float vs[256];
    __shared__ float qs[256];
    __shared__ float red[256][4];

    const int tid = threadIdx.x;
    const int gid = blockIdx.x;                     // 0..1023
    const int wg = (gid & 7) * 128 + (gid >> 3);    // bijective XCD chunking
    const int b = wg >> 4;                          // 0..63
    const int x = wg & 15;
    const int tn = x >> 2;                          // n-tile 0..3
    const int te = x & 3;                           // e-tile 0..3

    if (tid < 256) {
        vs[tid] = v[te * 256 + tid];
        qs[tid] = qh[b * DD + te * 256 + tid];
    }

    // global staging bases (pre-swizzled chunks; kt stride = 8192 B)
    const char* a0 = (const char*)(keysT + (((size_t)b * 8 + tn * 2) * 32) * 4096) + tid * 16;
    const char* a1 = a0 + 32 * 8192;
    const char* b0 = (const char*)(wkT + (((size_t)te * 2) * 32) * 4096) + tid * 16;
    const char* b1 = b0 + 32 * 8192;
    char* AsB = (char*)As;
    char* BsB = (char*)Bs;

    const int w = tid >> 6, lane = tid & 63;
    const int wm = w & 1, wn = w >> 1;
    const int lcol = lane & 15, quad = lane >> 4;
    const int qx = quad ^ ((lcol >> 1) & 3);  // read-side sub-block swizzle
    const int aofs = wm * 4096 + lcol * 32 + qx * 8;                          // + mi*512
    const int bofs = (wn >> 1) * 4096 + (wn & 1) * 2048 + lcol * 32 + qx * 8; // + ni*512

    f32x4 acc[8][4];
#pragma unroll
    for (int mi = 0; mi < 8; ++mi)
#pragma unroll
        for (int ni = 0; ni < 4; ++ni) acc[mi][ni] = (f32x4){0.f, 0.f, 0.f, 0.f};

    // prologue: stage slabs 0,1,2; wait slab0 landed (vmcnt(8) leaves 1,2 in flight)
#pragma unroll
    for (int s = 0; s < 3; ++s) {
        const size_t go = (size_t)s * 8192;
        GLOAD_LDS16(a0 + go, AsB + s * 16384 + tid * 16);
        GLOAD_LDS16(a1 + go, AsB + s * 16384 + 8192 + tid * 16);
        GLOAD_LDS16(b0 + go, BsB + s * 16384 + tid * 16);
        GLOAD_LDS16(b1 + go, BsB + s * 16384 + 8192 + tid * 16);
    }
    asm volatile("s_waitcnt vmcnt(8)" ::: "memory");
    __builtin_amdgcn_s_barrier();
    __builtin_amdgcn_sched_barrier(0);

#pragma unroll 1
    for (int kt = 0; kt < 29; ++kt) {
        PHASE(kt, kt + 3, "s_waitcnt vmcnt(8)");
    }
    PHASE(29, 32, "s_waitcnt vmcnt(4)");
    PHASE(30, 32, "s_waitcnt vmcnt(0)");
    PHASE(31, 32, "");

    // epilogue: C/D layout col=lane&15 (e), row=quad*4+reg (n)
    float part[8][4];
#pragma unroll
    for (int mi = 0; mi < 8; ++mi)
#pragma unroll
        for (int r = 0; r < 4; ++r) part[mi][r] = 0.f;
#pragma unroll
    for (int mi = 0; mi < 8; ++mi)
#pragma unroll
        for (int ni = 0; ni < 4; ++ni) {
            const int e = wn * 64 + ni * 16 + lcol;
            const float vv = vs[e];
            const float qv = qs[e];
#pragma unroll
            for (int r = 0; r < 4; ++r)
                part[mi][r] += vv * fast_tanh(qv + acc[mi][ni][r]);
        }
#pragma unroll
    for (int mi = 0; mi < 8; ++mi)
#pragma unroll
        for (int r = 0; r < 4; ++r) {
            float p = part[mi][r];
            p += __shfl_xor(p, 1);
            p += __shfl_xor(p, 2);
            p += __shfl_xor(p, 4);
            p += __shfl_xor(p, 8);
            if (lcol == 0) red[wm * 128 + mi * 16 + quad * 4 + r][wn] = p;
        }
    __syncthreads();
    if (tid < 256)
        atomicAdd(&scores[b * NN + tn * 256 + tid],
                  red[tid][0] + red[tid][1] + red[tid][2] + red[tid][3]);
}

// ---- k_sm: softmax ----
__global__ __launch_bounds__(256) void k_sm(const float* __restrict__ scores,
                                            float* __restrict__ alpha) {
    const int b = blockIdx.x;
    const int t = threadIdx.x;
    float x[4];
    float m = -1e30f;
#pragma unroll
    for (int j = 0; j < 4; ++j) {
        x[j] = scores[b * NN + t + 256 * j];
        m = fmaxf(m, x[j]);
    }
#pragma unroll
    for (int mask = 32; mask >= 1; mask >>= 1) m = fmaxf(m, __shfl_xor(m, mask));
    __shared__ float wred[4];
    __shared__ float wsum[4];
    const int wv = t >> 6;
    if ((t & 63) == 0) wred[wv] = m;
    __syncthreads();
    m = fmaxf(fmaxf(wred[0], wred[1]), fmaxf(wred[2], wred[3]));
    float s = 0.f;
#pragma unroll
    for (int j = 0; j < 4; ++j) {
        x[j] = expf(x[j] - m);
        s += x[j];
    }
#pragma unroll
    for (int mask = 32; mask >= 1; mask >>= 1) s += __shfl_xor(s, mask);
    if ((t & 63) == 0) wsum[wv] = s;
    __syncthreads();
    s = wsum[0] + wsum[1] + wsum[2] + wsum[3];
    const float inv = 1.f / s;
#pragma unroll
    for (int j = 0; j < 4; ++j) alpha[b * NN + t + 256 * j] = x[j] * inv;
}

// ---- k_ctx: context[b, kt*32..+32] = sum_n alpha[b,n]*keysT chunks ----
// Swizzle-aware: sub-block q of row g holds k-octet q ^ ((g>>1)&3).
__global__ __launch_bounds__(256) void k_ctx(const _Float16* __restrict__ keysT,
                                             const float* __restrict__ alpha,
                                             float* __restrict__ context) {
    __shared__ float al[NN];
    __shared__ float red[64][33];
    const int kt = blockIdx.x;  // 0..31
    const int b = blockIdx.y;   // 0..63
    const int t = threadIdx.x;
#pragma unroll
    for (int j = 0; j < 4; ++j) al[t + 256 * j] = alpha[b * NN + t + 256 * j];
    __syncthreads();

    const int p0 = t * 8;
    const int g = t >> 2;               // 0..63: n within half-chunk
    const int q = t & 3;                // physical sub-block
    const int qe = q ^ ((g >> 1) & 3);  // logical k-octet held
    float acc[8];
#pragma unroll
    for (int j = 0; j < 8; ++j) acc[j] = 0.f;

    for (int nt = 0; nt < 8; ++nt) {
        const _Float16* base = keysT + (((size_t)b * 8 + nt) * 32 + kt) * 4096;
#pragma unroll
        for (int r = 0; r < 2; ++r) {
            f16x8 kv = *(const f16x8*)(base + r * 2048 + p0);
            const float a = al[nt * 128 + r * 64 + g];
#pragma unroll
            for (int j = 0; j < 8; ++j) acc[j] = fmaf(a, (float)kv[j], acc[j]);
        }
    }
#pragma unroll
    for (int j = 0; j < 8; ++j) red[g][qe * 8 + j] = acc[j];
    __syncthreads();
    if (t < 32) {
        float s = 0.f;
#pragma unroll 8
        for (int n = 0; n < 64; ++n) s += red[n][t];
        context[(size_t)b * DD + kt * 32 + t] = s;
    }
}

// =========================== FALLBACK PATH (used if ws too small) ===========================
__global__ __launch_bounds__(256) void qh_fb(const float* __restrict__ h_t,
                                             const float* __restrict__ W_h,
                                             float* __restrict__ qh,
                                             float* __restrict__ scores) {
    __shared__ float hs[DD];
    const int b = blockIdx.y;
    const int e = blockIdx.x * 256 + threadIdx.x;
    scores[(blockIdx.y * 4 + blockIdx.x) * 256 + threadIdx.x] = 0.f;
    for (int i = threadIdx.x; i < DD; i += 256) hs[i] = h_t[b * DD + i];
    __syncthreads();
    const float4* wrow = (const float4*)(W_h + (size_t)e * DD);
    float acc = 0.f;
#pragma unroll 4
    for (int k4 = 0; k4 < DD / 4; ++k4) {
        float4 w = wrow[k4];
        acc = fmaf(w.x, hs[4 * k4 + 0], acc);
        acc = fmaf(w.y, hs[4 * k4 + 1], acc);
        acc = fmaf(w.z, hs[4 * k4 + 2], acc);
        acc = fmaf(w.w, hs[4 * k4 + 3], acc);
    }
    qh[b * DD + e] = acc;
}

#define SPAD 40
__device__ __forceinline__ void split16(const float4* __restrict__ src,
                                        unsigned short* hi, unsigned short* lo) {
    float x[16];
    float4 v0 = src[0], v1 = src[1], v2 = src[2], v3 = src[3];
    x[0] = v0.x; x[1] = v0.y; x[2] = v0.z; x[3] = v0.w;
    x[4] = v1.x; x[5] = v1.y; x[6] = v1.z; x[7] = v1.w;
    x[8] = v2.x; x[9] = v2.y; x[10] = v2.z; x[11] = v2.w;
    x[12] = v3.x; x[13] = v3.y; x[14] = v3.z; x[15] = v3.w;
#pragma unroll
    for (int i = 0; i < 16; ++i) {
        unsigned int u = __float_as_uint(x[i]);
        hi[i] = (unsigned short)(u >> 16);
        float hif = __uint_as_float(u & 0xFFFF0000u);
        float lof = x[i] - hif;
        lo[i] = (unsigned short)(__float_as_uint(lof) >> 16);
    }
}

__global__ __launch_bounds__(256, 2) void scores_fb(const float* __restrict__ keys,
                                                    const float* __restrict__ W_k,
                                                    const float* __restrict__ v,
                                                    const float* __restrict__ qh,
                                                    float* __restrict__ scores) {
    __shared__ unsigned short Ah[128 * SPAD];
    __shared__ unsigned short Al[128 * SPAD];
    __shared__ unsigned short Bh[128 * SPAD];
    __shared__ unsigned short Bl[128 * SPAD];
    __shared__ float vs[128];
    __shared__ float qs[128];
    __shared__ float red[128][2];

    const int tid = threadIdx.x;
    const int cp = blockIdx.x;
    const int rt = blockIdx.y;
    const int b = rt >> 3;
    const int n0 = (rt & 7) * 128;
    const int e0 = cp * 128;
    if (tid < 128) {
        vs[tid] = v[e0 + tid];
        qs[tid] = qh[b * DD + e0 + tid];
    }
    const float* Ag = keys + ((size_t)b * NN + n0) * DD;
    const float* Bg = W_k + (size_t)e0 * DD;
    const int w = tid >> 6;
    const int lane = tid & 63;
    const int wm = w & 1;
    const int we = w >> 1;
    const int lcol = lane & 15;
    const int quad = lane >> 4;
    f32x4 acc[4][4];
#pragma unroll
    for (int mi = 0; mi < 4; ++mi)
#pragma unroll
        for (int ni = 0; ni < 4; ++ni) acc[mi][ni] = (f32x4){0.f, 0.f, 0.f, 0.f};
    const int srow = tid >> 1;
    const int sseg = tid & 1;
    float4 pa[4], pb[4];
    {
        const float4* as = (const float4*)(Ag + (size_t)srow * DD + sseg * 16);
        const float4* bs = (const float4*)(Bg + (size_t)srow * DD + sseg * 16);
#pragma unroll
        for (int i = 0; i < 4; ++i) { pa[i] = as[i]; pb[i] = bs[i]; }
    }
    for (int kt = 0; kt < DD / 32; ++kt) {
        __syncthreads();
        {
            unsigned short hi[16], lo[16];
            split16(pa, hi, lo);
            u16x8* dh = (u16x8*)&Ah[srow * SPAD + sseg * 16];
            u16x8* dl = (u16x8*)&Al[srow * SPAD + sseg * 16];
            dh[0] = *(u16x8*)&hi[0]; dh[1] = *(u16x8*)&hi[8];
            dl[0] = *(u16x8*)&lo[0]; dl[1] = *(u16x8*)&lo[8];
            split16(pb, hi, lo);
            u16x8* eh = (u16x8*)&Bh[srow * SPAD + sseg * 16];
            u16x8* el = (u16x8*)&Bl[srow * SPAD + sseg * 16];
            eh[0] = *(u16x8*)&hi[0]; eh[1] = *(u16x8*)&hi[8];
            el[0] = *(u16x8*)&lo[0]; el[1] = *(u16x8*)&lo[8];
        }
        if (kt + 1 < DD / 32) {
            const int k0 = (kt + 1) * 32;
            const float4* as = (const float4*)(Ag + (size_t)srow * DD + k0 + sseg * 16);
            const float4* bs = (const float4*)(Bg + (size_t)srow * DD + k0 + sseg * 16);
#pragma unroll
            for (int i = 0; i < 4; ++i) { pa[i] = as[i]; pb[i] = bs[i]; }
        }
        __syncthreads();
        bf16x8 ah[4], al2[4], bh[4], bl2[4];
#pragma unroll
        for (int mi = 0; mi < 4; ++mi) {
            const int r = wm * 64 + mi * 16 + lcol;
            ah[mi] = *(const bf16x8*)&Ah[r * SPAD + quad * 8];
            al2[mi] = *(const bf16x8*)&Al[r * SPAD + quad * 8];
        }
#pragma unroll
        for (int ni = 0; ni < 4; ++ni) {
            const int r = we * 64 + ni * 16 + lcol;
            bh[ni] = *(const bf16x8*)&Bh[r * SPAD + quad * 8];
            bl2[ni] = *(const bf16x8*)&Bl[r * SPAD + quad * 8];
        }
#pragma unroll
        for (int mi = 0; mi < 4; ++mi)
#pragma unroll
            for (int ni = 0; ni < 4; ++ni) {
                acc[mi][ni] = __builtin_amdgcn_mfma_f32_16x16x32_bf16(ah[mi], bh[ni], acc[mi][ni], 0, 0, 0);
                acc[mi][ni] = __builtin_amdgcn_mfma_f32_16x16x32_bf16(ah[mi], bl2[ni], acc[mi][ni], 0, 0, 0);
                acc[mi][ni] = __builtin_amdgcn_mfma_f32_16x16x32_bf16(al2[mi], bh[ni], acc[mi][ni], 0, 0, 0);
            }
    }
    float part[4][4];
#pragma unroll
    for (int mi = 0; mi < 4; ++mi)
#pragma unroll
        for (int r = 0; r < 4; ++r) part[mi][r] = 0.f;
#pragma unroll
    for (int mi = 0; mi < 4; ++mi)
#pragma unroll
        for (int ni = 0; ni < 4; ++ni) {
            const int e = we * 64 + ni * 16 + lcol;
            const float vv = vs[e];
            const float qv = qs[e];
#pragma unroll
            for (int r = 0; r < 4; ++r)
                part[mi][r] += vv * fast_tanh(qv + acc[mi][ni][r]);
        }
#pragma unroll
    for (int mi = 0; mi < 4; ++mi)
#pragma unroll
        for (int r = 0; r < 4; ++r) {
            float p = part[mi][r];
            p += __shfl_xor(p, 1);
            p += __shfl_xor(p, 2);
            p += __shfl_xor(p, 4);
            p += __shfl_xor(p, 8);
            if (lcol == 0) red[wm * 64 + mi * 16 + quad * 4 + r][we] = p;
        }
    __syncthreads();
    if (tid < 128) atomicAdd(&scores[b * NN + n0 + tid], red[tid][0] + red[tid][1]);
}

__global__ __launch_bounds__(256) void sm_fb(const float* __restrict__ scores,
                                             float* __restrict__ alpha,
                                             float* __restrict__ context) {
    const int b = blockIdx.x;
    const int t = threadIdx.x;
#pragma unroll
    for (int j = 0; j < 4; ++j) context[b * DD + t + 256 * j] = 0.f;
    float x[4];
    float m = -1e30f;
#pragma unroll
    for (int j = 0; j < 4; ++j) {
        x[j] = scores[b * NN + t + 256 * j];
        m = fmaxf(m, x[j]);
    }
#pragma unroll
    for (int mask = 32; mask >= 1; mask >>= 1) m = fmaxf(m, __shfl_xor(m, mask));
    __shared__ float wred[4];
    __shared__ float wsum[4];
    const int wv = t >> 6;
    if ((t & 63) == 0) wred[wv] = m;
    __syncthreads();
    m = fmaxf(fmaxf(wred[0], wred[1]), fmaxf(wred[2], wred[3]));
    float s = 0.f;
#pragma unroll
    for (int j = 0; j < 4; ++j) {
        x[j] = expf(x[j] - m);
        s += x[j];
    }
#pragma unroll
    for (int mask = 32; mask >= 1; mask >>= 1) s += __shfl_xor(s, mask);
    if ((t & 63) == 0) wsum[wv] = s;
    __syncthreads();
    s = wsum[0] + wsum[1] + wsum[2] + wsum[3];
    const float inv = 1.f / s;
#pragma unroll
    for (int j = 0; j < 4; ++j) alpha[b * NN + t + 256 * j] = x[j] * inv;
}

__global__ __launch_bounds__(256) void ctx_fb(const float* __restrict__ keys,
                                              const float* __restrict__ alpha,
                                              float* __restrict__ context) {
    const int b = blockIdx.y;
    const int nc = blockIdx.x;
    const int t = threadIdx.x;
    __shared__ float al[64];
    if (t < 64) al[t] = alpha[b * NN + nc * 64 + t];
    __syncthreads();
    const float4* kp = (const float4*)(keys + ((size_t)b * NN + nc * 64) * DD);
    float4 acc = {0.f, 0.f, 0.f, 0.f};
#pragma unroll 4
    for (int n = 0; n < 64; ++n) {
        const float a = al[n];
        float4 kv = kp[(size_t)n * (DD / 4) + t];
        acc.x = fmaf(a, kv.x, acc.x);
        acc.y = fmaf(a, kv.y, acc.y);
        acc.z = fmaf(a, kv.z, acc.z);
        acc.w = fmaf(a, kv.w, acc.w);
    }
    float* cp = context + b * DD + 4 * t;
    atomicAdd(cp + 0, acc.x);
    atomicAdd(cp + 1, acc.y);
    atomicAdd(cp + 2, acc.z);
    atomicAdd(cp + 3, acc.w);
}

extern "C" void kernel_launch(void* const* d_in, const int* in_sizes, int n_in,
                              void* d_out, int out_size, void* d_ws, size_t ws_size,
                              hipStream_t stream) {
    const float* h_t = (const float*)d_in[0];
    const float* keys = (const float*)d_in[1];
    const float* W_h = (const float*)d_in[2];
    const float* W_k = (const float*)d_in[3];
    const float* v = (const float*)d_in[4];

    float* context = (float*)d_out;          // [B, D]
    float* alpha = (float*)d_out + BB * DD;  // [B, N]
    float* qh = (float*)d_ws;                // [B, D]
    float* scores = (float*)d_ws + BB * DD;  // [B, N]

    const size_t wkT_off = (size_t)2 * BB * DD * sizeof(float);  // 512 KB
    const size_t keysT_off = wkT_off + (size_t)DD * DD * 2;      // +2 MB
    const size_t need = keysT_off + (size_t)BB * NN * DD * 2;    // +128 MB

    if (ws_size >= need) {
        _Float16* wkT = (_Float16*)((char*)d_ws + wkT_off);
        _Float16* keysT = (_Float16*)((char*)d_ws + keysT_off);
        k_cvt<<<dim3(8, 65, 4), 256, 0, stream>>>(keys, W_k, keysT, wkT);
        k_qh<<<dim3(64, 8), 256, 0, stream>>>(h_t, W_h, qh, scores);
        k_sc<<<dim3(1024), 512, 0, stream>>>(keysT, wkT, v, qh, scores);
        k_sm<<<BB, 256, 0, stream>>>(scores, alpha);
        k_ctx<<<dim3(32, 64), 256, 0, stream>>>(keysT, alpha, context);
    } else {
        qh_fb<<<dim3(4, BB), 256, 0, stream>>>(h_t, W_h, qh, scores);
        scores_fb<<<dim3(8, 512), 256, 0, stream>>>(keys, W_k, v, qh, scores);
        sm_fb<<<BB, 256, 0, stream>>>(scores, alpha, context);
        ctx_fb<<<dim3(16, BB), 256, 0, stream>>>(keys, alpha, context);
    }
}